// Round 3
// baseline (163.137 us; speedup 1.0000x reference)
//
#include <hip/hip_runtime.h>
#include <hip/hip_bf16.h>
#include <stdint.h>

// B=8, S=2048, D=256. out[b,d] = (1/S) sum_k w_k v[b,k,d],
// w_k = sum_q P_qk / l_q,  P_qk = exp(s_qk) (0 for masked k), l_q = sum_k P_qk.
// pass1: QK^T bf16 MFMA -> P (fp16, MFMA-native tiles) + l_q.
// k_wred2: reduce P tiles over q -> w_k.  Fallback (small ws): recompute pass2.

typedef short short8 __attribute__((ext_vector_type(8)));
typedef float floatx4 __attribute__((ext_vector_type(4)));

#define MFMA16(a, b, c) __builtin_amdgcn_mfma_f32_16x16x32_bf16((a), (b), (c), 0, 0, 0)

static __device__ __forceinline__ unsigned short f2bf(float f) {
    union { float f; unsigned u; } v; v.f = f;
    unsigned r = v.u + 0x7fffu + ((v.u >> 16) & 1u);
    return (unsigned short)(r >> 16);
}
static __device__ __forceinline__ float bf2f(unsigned short h) {
    union { unsigned u; float f; } v; v.u = ((unsigned)h) << 16;
    return v.f;
}

// ---------------- k0: fp32 -> bf16 conversion (nodes + 3 weight mats) -------
__global__ __launch_bounds__(256) void k_convert(
    const float* __restrict__ nodes, const float* __restrict__ Wq,
    const float* __restrict__ Wk, const float* __restrict__ Wv,
    unsigned short* __restrict__ nbf, unsigned short* __restrict__ wbf)
{
    int unit = blockIdx.x * 256 + threadIdx.x;   // one unit = 8 elements
    const float* src;
    unsigned short* dst;
    int off;
    if (unit < 524288) {                          // 4194304 node elems
        src = nodes; dst = nbf; off = unit * 8;
    } else {
        int j = (unit - 524288) * 8;              // weight elem idx
        int m = j >> 16;
        int r = j & 65535;
        src = (m == 0) ? Wq : (m == 1 ? Wk : Wv);
        dst = wbf + m * 65536;
        off = r;
    }
    float4 a = *(const float4*)(src + off);
    float4 b = *(const float4*)(src + off + 4);
    short8 o;
    o[0] = f2bf(a.x); o[1] = f2bf(a.y); o[2] = f2bf(a.z); o[3] = f2bf(a.w);
    o[4] = f2bf(b.x); o[5] = f2bf(b.y); o[6] = f2bf(b.z); o[7] = f2bf(b.w);
    *(short8*)(dst + off) = o;
}

// ---------------- k1: projection GEMM, 128x128 LDS-tiled --------------------
__global__ __launch_bounds__(256) void k_proj2(
    const unsigned short* __restrict__ nbf,   // [16384][256] bf16
    const unsigned short* __restrict__ wbf,   // [3][256][256] bf16
    const float* __restrict__ bq, const float* __restrict__ bk,
    const float* __restrict__ bv,
    unsigned short* __restrict__ qb, unsigned short* __restrict__ kb,
    unsigned short* __restrict__ vb)
{
    __shared__ unsigned short As[128 * 64];   // 1024 chunks of 16B
    __shared__ unsigned short Bs[128 * 64];
    int tid = threadIdx.x, lane = tid & 63, wave = tid >> 6;
    int wm = wave & 1, wn = wave >> 1;
    int l15 = lane & 15, quad = lane >> 4;
    int mBase = blockIdx.x * 128;
    int nBase = blockIdx.y * 128;
    int z = blockIdx.z;
    const unsigned short* W = wbf + z * 65536;

    floatx4 acc[4][4] = {};

    int srow[4], scol[4];
#pragma unroll
    for (int i = 0; i < 4; ++i) {
        int p = i * 256 + tid;
        srow[i] = p >> 3;
        scol[i] = (p & 7) ^ (srow[i] & 7);
    }

    for (int kc = 0; kc < 256; kc += 64) {
#pragma unroll
        for (int i = 0; i < 4; ++i) {
            int p = i * 256 + tid;
            *(short8*)(&As[p * 8]) =
                *(const short8*)(nbf + (mBase + srow[i]) * 256 + kc + scol[i] * 8);
            *(short8*)(&Bs[p * 8]) =
                *(const short8*)(W + (nBase + srow[i]) * 256 + kc + scol[i] * 8);
        }
        __syncthreads();
#pragma unroll
        for (int ks = 0; ks < 2; ++ks) {
            int c8 = ks * 4 + quad;
            short8 af[4], bfr[4];
#pragma unroll
            for (int i = 0; i < 4; ++i) {
                int row = wm * 64 + i * 16 + l15;
                af[i] = *(const short8*)(&As[(row * 8 + (c8 ^ (row & 7))) * 8]);
            }
#pragma unroll
            for (int i = 0; i < 4; ++i) {
                int row = wn * 64 + i * 16 + l15;
                bfr[i] = *(const short8*)(&Bs[(row * 8 + (c8 ^ (row & 7))) * 8]);
            }
#pragma unroll
            for (int mi = 0; mi < 4; ++mi)
#pragma unroll
                for (int ni = 0; ni < 4; ++ni)
                    acc[mi][ni] = MFMA16(af[mi], bfr[ni], acc[mi][ni]);
        }
        __syncthreads();
    }

    const float* bias = (z == 0) ? bq : (z == 1 ? bk : bv);
    unsigned short* out = (z == 0) ? qb : (z == 1 ? kb : vb);
    float scale = (z == 0) ? 0.0625f : 1.0f;
#pragma unroll
    for (int mi = 0; mi < 4; ++mi)
#pragma unroll
        for (int ni = 0; ni < 4; ++ni) {
            int col = nBase + wn * 64 + ni * 16 + l15;
            float bval = bias[col];
#pragma unroll
            for (int r = 0; r < 4; ++r) {
                int row = mBase + wm * 64 + mi * 16 + quad * 4 + r;
                out[row * 256 + col] = f2bf((acc[mi][ni][r] + bval) * scale);
            }
        }
}

// ---------------- pass1: QK^T, exp, l_q; cache P in MFMA-native fp16 tiles --
// grid (16, 8, 8): (q-tile of 128, key-split of 256, batch); 1024 blocks.
// kt: XOR-swizzled 16B chunks, 64 rows x 32 chunks (32KB).
// P tile: per (b,qblk,wave,kcIdx,nt): 64 lanes x 16B (8 fp16, regs mi*4+r).
template <bool STORE_P>
__global__ __launch_bounds__(256) void k_pass1(
    const unsigned short* __restrict__ qb, const unsigned short* __restrict__ kb,
    const int* __restrict__ mask, float* __restrict__ lsum_g,
    unsigned short* __restrict__ pbuf)
{
    __shared__ unsigned short kt[64 * 32 * 8];
    __shared__ float mf[64];
    int tid = threadIdx.x, lane = tid & 63, wave = tid >> 6;
    int l15 = lane & 15, quad = lane >> 4;
    int b = blockIdx.z;
    int qBase = blockIdx.x * 128 + wave * 32;
    int kStart = blockIdx.y * 256;

    short8 qf[2][8];
#pragma unroll
    for (int mi = 0; mi < 2; ++mi)
#pragma unroll
        for (int ks = 0; ks < 8; ++ks)
            qf[mi][ks] = *(const short8*)(qb + (b * 2048 + qBase + mi * 16 + l15) * 256 + ks * 32 + quad * 8);

    float ls[2][4] = {};
    for (int kc = kStart; kc < kStart + 256; kc += 64) {
#pragma unroll
        for (int u = tid; u < 2048; u += 256) {
            int row = u >> 5, cu = u & 31;
            int slot = row * 32 + (cu ^ (row & 7));
            *(uint4*)(&kt[slot * 8]) = *(const uint4*)(kb + (b * 2048 + kc) * 256 + u * 8);
        }
        if (tid < 64) mf[tid] = mask[b * 2048 + kc + tid] ? 0.0f : -1e30f;
        __syncthreads();
#pragma unroll
        for (int nt = 0; nt < 4; ++nt) {
            int row = nt * 16 + l15;
            short8 kf[8];
#pragma unroll
            for (int ks = 0; ks < 8; ++ks) {
                int c8 = ks * 4 + quad;
                kf[ks] = *(const short8*)(&kt[(row * 32 + (c8 ^ (row & 7))) * 8]);
            }
            floatx4 acc[2] = {};
#pragma unroll
            for (int ks = 0; ks < 8; ++ks) {
                acc[0] = MFMA16(qf[0][ks], kf[ks], acc[0]);
                acc[1] = MFMA16(qf[1][ks], kf[ks], acc[1]);
            }
            float bvv = mf[row];
            short8 hh;
#pragma unroll
            for (int mi = 0; mi < 2; ++mi)
#pragma unroll
                for (int r = 0; r < 4; ++r) {
                    float e = __expf(acc[mi][r] + bvv);
                    ls[mi][r] += e;
                    if (STORE_P) {
                        union { _Float16 h; short s; } u; u.h = (_Float16)e;
                        hh[mi * 4 + r] = u.s;
                    }
                }
            if (STORE_P) {
                size_t tileIdx = ((((size_t)b * 16 + blockIdx.x) * 4 + wave) * 32 + (kc >> 6)) * 4 + nt;
                *(short8*)(pbuf + tileIdx * 512 + lane * 8) = hh;
            }
        }
        __syncthreads();
    }
#pragma unroll
    for (int mi = 0; mi < 2; ++mi)
#pragma unroll
        for (int r = 0; r < 4; ++r) {
            float v = ls[mi][r];
            v += __shfl_xor(v, 1); v += __shfl_xor(v, 2);
            v += __shfl_xor(v, 4); v += __shfl_xor(v, 8);
            if (l15 == 0)
                atomicAdd(&lsum_g[b * 2048 + qBase + mi * 16 + quad * 4 + r], v);
        }
}

// ---------------- k_wred2: w_k = sum_q P[q][k] / l_q from fp16 tiles --------
// grid (32 kc, 8 b); block 512 = 8 waves: wave -> (qhalf = w>>2, nt = w&3).
__global__ __launch_bounds__(512) void k_wred2(
    const unsigned short* __restrict__ pbuf, const float* __restrict__ lsum_g,
    float* __restrict__ wsum_g)
{
    __shared__ float linv_s[2048];   // [qg][quad][j]
    int tid = threadIdx.x, lane = tid & 63, wave = tid >> 6;
    int l15 = lane & 15, quad = lane >> 4;
    int b = blockIdx.y, kc = blockIdx.x;
    int nt = wave & 3;
    int qg0 = (wave >> 2) * 32;

    for (int idx = tid; idx < 2048; idx += 512) {
        int qg = idx >> 5, qd = (idx >> 3) & 3, j = idx & 7;
        int q = qg * 32 + (j >> 2) * 16 + qd * 4 + (j & 3);
        linv_s[idx] = 1.0f / lsum_g[b * 2048 + q];
    }
    __syncthreads();

    float acc = 0.f;
#pragma unroll 4
    for (int qg = qg0; qg < qg0 + 32; ++qg) {
        size_t tileIdx = ((((size_t)b * 16 + (qg >> 2)) * 4 + (qg & 3)) * 32 + kc) * 4 + nt;
        short8 hv = *(const short8*)(pbuf + tileIdx * 512 + lane * 8);
        const float* lv = &linv_s[(qg * 4 + quad) * 8];
#pragma unroll
        for (int j = 0; j < 8; ++j) {
            union { short s; _Float16 h; } u; u.s = hv[j];
            acc += (float)u.h * lv[j];
        }
    }
    acc += __shfl_xor(acc, 16);
    acc += __shfl_xor(acc, 32);
    if (lane < 16)
        atomicAdd(&wsum_g[b * 2048 + kc * 64 + nt * 16 + l15], acc);
}

// ---------------- pass2 (fallback, recompute): proven round-1 path ----------
#define LDSW 264
__global__ __launch_bounds__(256) void k_pass2(
    const unsigned short* __restrict__ qb, const unsigned short* __restrict__ kb,
    const int* __restrict__ mask, const float* __restrict__ lsum_g,
    float* __restrict__ wsum_g)
{
    __shared__ unsigned short kt[64 * LDSW];
    __shared__ float mf[64];
    int tid = threadIdx.x, lane = tid & 63, wave = tid >> 6;
    int l15 = lane & 15, quad = lane >> 4;
    int b = blockIdx.z;
    int qBase = blockIdx.x * 128 + wave * 32;
    int kStart = blockIdx.y * 512;

    short8 qf[2][8];
    float linv[2][4];
#pragma unroll
    for (int mi = 0; mi < 2; ++mi) {
#pragma unroll
        for (int ks = 0; ks < 8; ++ks)
            qf[mi][ks] = *(const short8*)(qb + (b * 2048 + qBase + mi * 16 + l15) * 256 + ks * 32 + quad * 8);
#pragma unroll
        for (int r = 0; r < 4; ++r)
            linv[mi][r] = 1.0f / lsum_g[b * 2048 + qBase + mi * 16 + quad * 4 + r];
    }

    for (int kc = kStart; kc < kStart + 512; kc += 64) {
#pragma unroll
        for (int u = tid; u < 2048; u += 256) {
            int row = u >> 5, cu = u & 31;
            *(uint4*)(&kt[row * LDSW + cu * 8]) = *(const uint4*)(kb + (b * 2048 + kc) * 256 + u * 8);
        }
        if (tid < 64) mf[tid] = mask[b * 2048 + kc + tid] ? 1.0f : 0.0f;
        __syncthreads();
#pragma unroll
        for (int nt = 0; nt < 4; ++nt) {
            short8 kf[8];
            const unsigned short* base = &kt[(nt * 16 + l15) * LDSW + quad * 8];
#pragma unroll
            for (int ks = 0; ks < 8; ++ks) kf[ks] = *(const short8*)(base + ks * 32);
            floatx4 acc[2] = {};
#pragma unroll
            for (int ks = 0; ks < 8; ++ks) {
                acc[0] = MFMA16(qf[0][ks], kf[ks], acc[0]);
                acc[1] = MFMA16(qf[1][ks], kf[ks], acc[1]);
            }
            float mv = mf[nt * 16 + l15];
            float part = 0.f;
#pragma unroll
            for (int mi = 0; mi < 2; ++mi)
#pragma unroll
                for (int r = 0; r < 4; ++r)
                    part += mv * __expf(fminf(acc[mi][r], 30.f)) * linv[mi][r];
            part += __shfl_xor(part, 16);
            part += __shfl_xor(part, 32);
            if (lane < 16)
                atomicAdd(&wsum_g[b * 2048 + kc + nt * 16 + lane], part);
        }
        __syncthreads();
    }
}

// ---------------- k4: out[b,d] = (1/S) sum_k w[b,k] * v[b,k,d] --------------
__global__ __launch_bounds__(256) void k_out(
    const float* __restrict__ wsum_g, const unsigned short* __restrict__ vb,
    float* __restrict__ outp)
{
    int b = blockIdx.y;
    int d = threadIdx.x;
    int k0 = blockIdx.x * 128;
    float acc = 0.f;
#pragma unroll 4
    for (int k = k0; k < k0 + 128; ++k) {
        float wv = wsum_g[b * 2048 + k];
        acc += wv * bf2f(vb[(b * 2048 + k) * 256 + d]);
    }
    atomicAdd(&outp[b * 256 + d], acc * (1.0f / 2048.0f));
}

extern "C" void kernel_launch(void* const* d_in, const int* in_sizes, int n_in,
                              void* d_out, int out_size, void* d_ws, size_t ws_size,
                              hipStream_t stream)
{
    const float* nodes = (const float*)d_in[0];
    const int*   mask  = (const int*)d_in[1];
    const float* Wq    = (const float*)d_in[2];
    const float* bq    = (const float*)d_in[3];
    const float* Wk    = (const float*)d_in[4];
    const float* bk    = (const float*)d_in[5];
    const float* Wv    = (const float*)d_in[6];
    const float* bv    = (const float*)d_in[7];
    float* out = (float*)d_out;

    // workspace layout (ushort units). X holds nbf+wbf (convert/proj lifetime),
    // reused for P tiles (pass1 onward) in the P path.
    unsigned short* qb  = (unsigned short*)d_ws;        // 16384*256
    unsigned short* kb  = qb + 4194304;
    unsigned short* vb  = kb + 4194304;
    float* lsum = (float*)(vb + 4194304);               // 16384
    float* wsum = lsum + 16384;                         // 16384
    unsigned short* X   = (unsigned short*)(wsum + 16384);
    unsigned short* nbf = X;                            // 4194304
    unsigned short* wbf = X + 4194304;                  // 196608
    unsigned short* pbuf = X;                           // 33554432 (P path)

    bool useP = ws_size >= 92500000;

    hipMemsetAsync(lsum, 0, 16384 * sizeof(float), stream);
    hipMemsetAsync(wsum, 0, 16384 * sizeof(float), stream);
    hipMemsetAsync(d_out, 0, 2048 * sizeof(float), stream);

    k_convert<<<2144, 256, 0, stream>>>(nodes, Wq, Wk, Wv, nbf, wbf);
    k_proj2<<<dim3(128, 2, 3), 256, 0, stream>>>(nbf, wbf, bq, bk, bv, qb, kb, vb);
    if (useP) {
        k_pass1<true><<<dim3(16, 8, 8), 256, 0, stream>>>(qb, kb, mask, lsum, pbuf);
        k_wred2<<<dim3(32, 8), 512, 0, stream>>>(pbuf, lsum, wsum);
    } else {
        k_pass1<false><<<dim3(16, 8, 8), 256, 0, stream>>>(qb, kb, mask, lsum, pbuf);
        k_pass2<<<dim3(16, 4, 8), 256, 0, stream>>>(qb, kb, mask, lsum, wsum);
    }
    k_out<<<dim3(16, 8), 256, 0, stream>>>(wsum, vb, out);
}